// Round 11
// baseline (80.907 us; speedup 1.0000x reference)
//
#include <hip/hip_runtime.h>
#include <hip/hip_bf16.h>

typedef __attribute__((ext_vector_type(8))) short bf16x8;
typedef __attribute__((ext_vector_type(4))) short short4v;
typedef __attribute__((ext_vector_type(4))) float f32x4;

#define B_SZ 8
#define T_SZ 2048
#define C_SZ 768
#define H_SZ 64

__device__ __forceinline__ short f2bs(float f){
  __hip_bfloat16 h = __float2bfloat16(f);
  short s; __builtin_memcpy(&s, &h, 2); return s;
}
__device__ __forceinline__ f32x4 vmax4(f32x4 a, f32x4 b){
  f32x4 r; r[0]=fmaxf(a[0],b[0]); r[1]=fmaxf(a[1],b[1]);
  r[2]=fmaxf(a[2],b[2]); r[3]=fmaxf(a[3],b[3]); return r;
}
// async global->LDS, 16B/lane; dest = wave-uniform base + lane*16; unsinkable by compiler
__device__ __forceinline__ void gload16(const void* g, void* l){
  __builtin_amdgcn_global_load_lds(
    (const __attribute__((address_space(1))) unsigned int*)g,
    (__attribute__((address_space(3))) unsigned int*)l, 16, 0, 0);
}

// --- K0: Wt transpose (blocks 0-35) + log2-scaled bias table (blocks 36-43) ---
__global__ __launch_bounds__(256) void prep_wt(const float* __restrict__ Wq, const float* __restrict__ Wk,
                        const float* __restrict__ Wv, const float* __restrict__ bias,
                        short* __restrict__ Wt, float* __restrict__ bsc){
  int tid = threadIdx.x;
  if (blockIdx.x >= 36){
    int i = (blockIdx.x - 36)*256 + tid;
    bsc[i] = bias[i] * 1.44269504f;         // log2e — softmax in exp2 domain
    return;
  }
  __shared__ float tile[64][65];
  int mat = blockIdx.x / 12, kblk = blockIdx.x % 12;
  const float* W = (mat == 0) ? Wq : (mat == 1 ? Wk : Wv);
  int k0 = kblk * 64;
  int r = tid >> 2, cq = (tid & 3) * 16;
  #pragma unroll
  for (int i = 0; i < 4; ++i){
    float4 v = *reinterpret_cast<const float4*>(&W[(k0 + r)*H_SZ + cq + i*4]);
    tile[r][cq + i*4 + 0] = v.x; tile[r][cq + i*4 + 1] = v.y;
    tile[r][cq + i*4 + 2] = v.z; tile[r][cq + i*4 + 3] = v.w;
  }
  __syncthreads();
  int n = tid >> 2, kq = (tid & 3) * 16;
  bf16x8 o0, o1;
  #pragma unroll
  for (int e = 0; e < 8; ++e){
    o0[e] = f2bs(tile[kq + e][n]);
    o1[e] = f2bs(tile[kq + 8 + e][n]);
  }
  *reinterpret_cast<bf16x8*>(&Wt[(mat*64 + n)*C_SZ + k0 + kq])     = o0;
  *reinterpret_cast<bf16x8*>(&Wt[(mat*64 + n)*C_SZ + k0 + kq + 8]) = o1;
}

// --- K1: QKV GEMM, A and B async-staged via global_load_lds, double-buffered ---
__global__ __launch_bounds__(512, 2) void qkv_gemm(const float* __restrict__ x, const short* __restrict__ Wt,
                         short* __restrict__ qb, short* __restrict__ kb, short* __restrict__ vT){
  __shared__ float As[2][2048];             // 16 KB: 32 rows x 64 fp32, chunk16-swizzled
  __shared__ short Bs[2][12288];            // 48 KB: 192 rows x 64 bf16, chunk16-swizzled
  int tid = threadIdx.x;
  int wv = tid >> 6, lane = tid & 63, lhi = lane >> 4, llo = lane & 15;
  int wm = wv >> 2, wn = wv & 3;
  long R0 = (long)blockIdx.x * 32;

  int srow = tid >> 4;
  int schunk = (tid & 15) ^ (srow & 7);
  const float* gsrcA = &x[(R0 + srow)*C_SZ + schunk*4];
  float* ldstA = &As[0][wv*256];

  int bn = tid >> 3;
  int bc = (tid & 7) ^ (bn & 7);
  const short* gsrcB0 = &Wt[(  0 + bn)*C_SZ + bc*8];
  const short* gsrcB1 = &Wt[( 64 + bn)*C_SZ + bc*8];
  const short* gsrcB2 = &Wt[(128 + bn)*C_SZ + bc*8];
  short* ldstB = &Bs[0][wv*512];

  f32x4 acc[3];
  #pragma unroll
  for (int j = 0; j < 3; ++j) acc[j] = (f32x4){0.f,0.f,0.f,0.f};

  int rr = wm*16 + llo;
  int r7 = rr & 7, lhi2 = lhi*2;
  int c0 = ((lhi2    ) ^ r7) << 2;
  int c1 = ((lhi2 + 1) ^ r7) << 2;
  int c2 = ((lhi2 + 8) ^ r7) << 2;
  int c3 = ((lhi2 + 9) ^ r7) << 2;
  int nrow[3];
  #pragma unroll
  for (int j = 0; j < 3; ++j) nrow[j] = (wn*48 + j*16 + llo)*64;
  int llo7 = llo & 7;
  int bo0 = ((    lhi) ^ llo7)*8;
  int bo1 = ((4 + lhi) ^ llo7)*8;

#define STAGE(T, BUF) { \
    gload16(gsrcA  + (T)*64, ldstA + (BUF)*2048); \
    gload16(gsrcB0 + (T)*64, ldstB + (BUF)*12288); \
    gload16(gsrcB1 + (T)*64, ldstB + (BUF)*12288 + 4096); \
    gload16(gsrcB2 + (T)*64, ldstB + (BUF)*12288 + 8192); }

  STAGE(0, 0);
  __syncthreads();

  for (int t = 0; t < 12; ++t){
    int cb = t & 1;
    if (t < 11) STAGE(t + 1, cb ^ 1);
    const float* Ar = &As[cb][rr*64];
    f32x4 a0 = *reinterpret_cast<const f32x4*>(Ar + c0);
    f32x4 a1 = *reinterpret_cast<const f32x4*>(Ar + c1);
    f32x4 a2 = *reinterpret_cast<const f32x4*>(Ar + c2);
    f32x4 a3 = *reinterpret_cast<const f32x4*>(Ar + c3);
    bf16x8 af0, af1;
    #pragma unroll
    for (int e = 0; e < 4; ++e){
      af0[e]   = f2bs(a0[e]); af0[4+e] = f2bs(a1[e]);
      af1[e]   = f2bs(a2[e]); af1[4+e] = f2bs(a3[e]);
    }
    const short* Br = &Bs[cb][0];
    #pragma unroll
    for (int j = 0; j < 3; ++j){
      bf16x8 b0 = *reinterpret_cast<const bf16x8*>(Br + nrow[j] + bo0);
      bf16x8 b1 = *reinterpret_cast<const bf16x8*>(Br + nrow[j] + bo1);
      acc[j] = __builtin_amdgcn_mfma_f32_16x16x32_bf16(af0, b0, acc[j], 0, 0, 0);
      acc[j] = __builtin_amdgcn_mfma_f32_16x16x32_bf16(af1, b1, acc[j], 0, 0, 0);
    }
    __syncthreads();
  }
#undef STAGE

  long mbase = R0 + wm*16 + lhi*4;
  #pragma unroll
  for (int j = 0; j < 3; ++j){
    int n = wn*48 + j*16 + llo;
    int mat = n >> 6, c = n & 63;
    if (mat == 2){
      long b = mbase >> 11, t = mbase & 2047;
      short4v p;
      #pragma unroll
      for (int reg = 0; reg < 4; ++reg) p[reg] = f2bs(acc[j][reg]);
      *reinterpret_cast<short4v*>(&vT[(b*H_SZ + c)*T_SZ + t]) = p;
    } else {
      short* dst = (mat == 0) ? qb : kb;
      #pragma unroll
      for (int reg = 0; reg < 4; ++reg)
        dst[(mbase + reg)*H_SZ + c] = f2bs(acc[j][reg]);
    }
  }
}

// --- K2: flash attention — shared-KV dual q-tile + affine-bias fast/slow path,
//     hoisted V loads; l kept EXACT in f32 per-lane partials (R8 numerics) ---
__global__ __launch_bounds__(512, 4) void attn_fwd(const short* __restrict__ qb, const short* __restrict__ kb,
                        const short* __restrict__ vT, const float* __restrict__ bsc,
                        float* __restrict__ out){
  __shared__ float bias_s[2048];            // 8 KB
  __shared__ short P_lds[8][2][1152];       // 36.9 KB; aliased as o_part during merge
  __shared__ float m_part[8][16];
  __shared__ float l_part[8][4][16];        // per-lhi f32 l partials (exact)
  float* OP = (float*)&P_lds[0][0][0];      // merge view: [w][row][d] @ w*1152 + row*65 + d

  int tid = threadIdx.x;
  for (int i = tid; i < 2048; i += 512) bias_s[i] = bsc[i];

  int wv = tid >> 6, lane = tid & 63, lhi = lane >> 4, llo = lane & 15;
  int b = blockIdx.x & 7, jj = blockIdx.x >> 3;   // batch -> XCD affinity
  int qtA = jj, qtB = 127 - jj;             // qtA kv-range is a subset of qtB's
  int nktA = (qtA >> 2) + 1, nktB = (qtB >> 2) + 1;
  int laneoff = llo - 4*lhi - 51;           // affine bias base (per-lane constant)

  const short* qrA = &qb[((long)(b*T_SZ + qtA*16 + llo))*H_SZ + lhi*8];
  const short* qrB = &qb[((long)(b*T_SZ + qtB*16 + llo))*H_SZ + lhi*8];
  bf16x8 qfA0 = *reinterpret_cast<const bf16x8*>(qrA);
  bf16x8 qfA1 = *reinterpret_cast<const bf16x8*>(qrA + 32);
  bf16x8 qfB0 = *reinterpret_cast<const bf16x8*>(qrB);
  bf16x8 qfB1 = *reinterpret_cast<const bf16x8*>(qrB + 32);
  const short* kbase = kb + (long)b*T_SZ*H_SZ;
  const short* vbase = vT + (long)b*H_SZ*T_SZ;
  __syncthreads();

  float mA = -1e30f, lA = 0.f, mB = -1e30f, lB = 0.f;
  f32x4 oA[4], oB[4];
  #pragma unroll
  for (int df = 0; df < 4; ++df){ oA[df] = (f32x4){0.f,0.f,0.f,0.f}; oB[df] = (f32x4){0.f,0.f,0.f,0.f}; }

  // softmax: affine-bias fast/slow path, defer-max, exact f32 l, P->LDS->B-frag
#define SM(S, M, L, O, DQ, TI, PB0, PB1) {                                    \
    int bidx = (DQ) + laneoff;                                                \
    if ((DQ) >= 64){                                                          \
      _Pragma("unroll") for (int f = 0; f < 4; ++f)                           \
        _Pragma("unroll") for (int rg = 0; rg < 4; ++rg)                      \
          S[f][rg] = fmaf(S[f][rg], 0.18033688f, bias_s[bidx + (51-16*f-rg)]);\
    } else {                                                                  \
      _Pragma("unroll") for (int f = 0; f < 4; ++f)                           \
        _Pragma("unroll") for (int rg = 0; rg < 4; ++rg){                     \
          int rel = bidx + (51-16*f-rg);                                      \
          float bv = bias_s[rel > 0 ? rel : 0];                               \
          S[f][rg] = (rel >= 0) ? fmaf(S[f][rg], 0.18033688f, bv) : -1e30f; } \
    }                                                                         \
    f32x4 tm = vmax4(vmax4(S[0], S[1]), vmax4(S[2], S[3]));                   \
    float pmax = fmaxf(fmaxf(tm[0], tm[1]), fmaxf(tm[2], tm[3]));             \
    if (!__all(pmax <= M + 8.0f)){                                            \
      float rm = fmaxf(pmax, __shfl_xor(pmax, 16));                           \
      rm = fmaxf(rm, __shfl_xor(rm, 32));                                     \
      float mnew = fmaxf(M, rm);                                              \
      float corr = exp2f(M - mnew);                                           \
      M = mnew; L *= corr;                                                    \
      _Pragma("unroll") for (int df = 0; df < 4; ++df) O[df] = O[df]*corr; }  \
    _Pragma("unroll") for (int f = 0; f < 4; ++f){                            \
      short4v pk;                                                             \
      _Pragma("unroll") for (int rg = 0; rg < 4; ++rg){                       \
        float p = exp2f(S[f][rg] - M);                                        \
        S[f][rg] = p; pk[rg] = f2bs(p); }                                     \
      *reinterpret_cast<short4v*>(&P_lds[wv][TI][llo*72 + f*16 + lhi*4]) = pk; } \
    f32x4 va = (S[0] + S[1]) + (S[2] + S[3]);                                 \
    L += (va[0] + va[1]) + (va[2] + va[3]);                                   \
    PB0 = *reinterpret_cast<const bf16x8*>(&P_lds[wv][TI][llo*72 + lhi*8]);   \
    PB1 = *reinterpret_cast<const bf16x8*>(&P_lds[wv][TI][llo*72 + 32 + lhi*8]); }

  for (int c = wv; c < nktB; c += 8){       // each kv-tile loaded ONCE, used by both q-tiles
    int kv0 = c * 64;
    bool doA = c < nktA;
    f32x4 sA[4], sB[4];
    #pragma unroll
    for (int f = 0; f < 4; ++f){
      const short* kr = kbase + (long)(kv0 + f*16 + llo)*H_SZ + lhi*8;
      bf16x8 k0 = *reinterpret_cast<const bf16x8*>(kr);
      bf16x8 k1 = *reinterpret_cast<const bf16x8*>(kr + 32);
      f32x4 t = (f32x4){0.f,0.f,0.f,0.f};
      t = __builtin_amdgcn_mfma_f32_16x16x32_bf16(k0, qfB0, t, 0, 0, 0);
      t = __builtin_amdgcn_mfma_f32_16x16x32_bf16(k1, qfB1, t, 0, 0, 0);
      sB[f] = t;
      f32x4 u = (f32x4){0.f,0.f,0.f,0.f};
      u = __builtin_amdgcn_mfma_f32_16x16x32_bf16(k0, qfA0, u, 0, 0, 0);
      u = __builtin_amdgcn_mfma_f32_16x16x32_bf16(k1, qfA1, u, 0, 0, 0);
      sA[f] = u;
    }
    // V loads issued BEFORE softmax — latency flies over the exp2 chains
    bf16x8 vf0[4], vf1[4];
    #pragma unroll
    for (int d = 0; d < 4; ++d){
      const short* vr = vbase + (long)(d*16 + llo)*T_SZ + kv0 + lhi*8;
      vf0[d] = *reinterpret_cast<const bf16x8*>(vr);
      vf1[d] = *reinterpret_cast<const bf16x8*>(vr + 32);
    }
    bf16x8 pbB0, pbB1;
    SM(sB, mB, lB, oB, (qtB*16 - kv0), 1, pbB0, pbB1);
    if (doA){
      bf16x8 pbA0, pbA1;
      SM(sA, mA, lA, oA, (qtA*16 - kv0), 0, pbA0, pbA1);
      #pragma unroll
      for (int df = 0; df < 4; ++df){
        oB[df] = __builtin_amdgcn_mfma_f32_16x16x32_bf16(vf0[df], pbB0, oB[df], 0, 0, 0);
        oB[df] = __builtin_amdgcn_mfma_f32_16x16x32_bf16(vf1[df], pbB1, oB[df], 0, 0, 0);
        oA[df] = __builtin_amdgcn_mfma_f32_16x16x32_bf16(vf0[df], pbA0, oA[df], 0, 0, 0);
        oA[df] = __builtin_amdgcn_mfma_f32_16x16x32_bf16(vf1[df], pbA1, oA[df], 0, 0, 0);
      }
    } else {
      #pragma unroll
      for (int df = 0; df < 4; ++df){
        oB[df] = __builtin_amdgcn_mfma_f32_16x16x32_bf16(vf0[df], pbB0, oB[df], 0, 0, 0);
        oB[df] = __builtin_amdgcn_mfma_f32_16x16x32_bf16(vf1[df], pbB1, oB[df], 0, 0, 0);
      }
    }
  }
#undef SM

  // two-phase merge (B then A); o_part aliases P_lds region; l exact per-lhi partials
#define MERGE(O, M, L, QT) {                                                \
    _Pragma("unroll") for (int df = 0; df < 4; ++df)                        \
      _Pragma("unroll") for (int rg = 0; rg < 4; ++rg)                      \
        OP[wv*1152 + llo*65 + df*16 + lhi*4 + rg] = O[df][rg];              \
    l_part[wv][lhi][llo] = L;                                               \
    if (lhi == 0) m_part[wv][llo] = M;                                      \
    __syncthreads();                                                        \
    { int idx = tid;                                                        \
      _Pragma("unroll") for (int rep = 0; rep < 2; ++rep){                  \
        int row = idx >> 6, d = idx & 63;                                   \
        float mstar = m_part[0][row];                                       \
        _Pragma("unroll") for (int w = 1; w < 8; ++w)                       \
          mstar = fmaxf(mstar, m_part[w][row]);                             \
        float lsum = 0.f, osum = 0.f;                                       \
        _Pragma("unroll") for (int w = 0; w < 8; ++w){                      \
          float sc = exp2f(m_part[w][row] - mstar);                         \
          lsum += sc * (l_part[w][0][row] + l_part[w][1][row]               \
                      + l_part[w][2][row] + l_part[w][3][row]);             \
          osum += sc * OP[w*1152 + row*65 + d]; }                           \
        out[((long)(b*T_SZ + (QT)*16 + row))*H_SZ + d] = osum / lsum;       \
        idx += 512; } }                                                     \
    __syncthreads(); }

  MERGE(oB, mB, lB, qtB);
  MERGE(oA, mA, lA, qtA);
#undef MERGE
}

extern "C" void kernel_launch(void* const* d_in, const int* in_sizes, int n_in,
                              void* d_out, int out_size, void* d_ws, size_t ws_size,
                              hipStream_t stream){
  const float* x    = (const float*)d_in[0];
  const float* Wq   = (const float*)d_in[1];
  const float* Wk   = (const float*)d_in[2];
  const float* Wv   = (const float*)d_in[3];
  const float* bias = (const float*)d_in[4];
  float* out = (float*)d_out;

  const size_t NTOK = (size_t)B_SZ * T_SZ * H_SZ;   // 1,048,576
  short* qb = (short*)d_ws;
  short* kb = qb + NTOK;
  short* vT = kb + NTOK;
  short* Wt = vT + NTOK;                            // 192*768 shorts
  float* bsc = (float*)(Wt + 192*C_SZ);             // 2048 floats

  prep_wt<<<44, 256, 0, stream>>>(Wq, Wk, Wv, bias, Wt, bsc);
  qkv_gemm<<<512, 512, 0, stream>>>(x, Wt, qb, kb, vT);
  attn_fwd<<<512, 512, 0, stream>>>(qb, kb, vT, bsc, out);
}

// Round 12
// 58.300 us; speedup vs baseline: 1.3878x; 1.3878x over previous
//
#include <hip/hip_runtime.h>
#include <hip/hip_bf16.h>

typedef __attribute__((ext_vector_type(8))) short bf16x8;
typedef __attribute__((ext_vector_type(4))) short short4v;
typedef __attribute__((ext_vector_type(4))) float f32x4;

#define B_SZ 8
#define T_SZ 2048
#define C_SZ 768
#define H_SZ 64

__device__ __forceinline__ short f2bs(float f){
  __hip_bfloat16 h = __float2bfloat16(f);
  short s; __builtin_memcpy(&s, &h, 2); return s;
}
__device__ __forceinline__ f32x4 vmax4(f32x4 a, f32x4 b){
  f32x4 r; r[0]=fmaxf(a[0],b[0]); r[1]=fmaxf(a[1],b[1]);
  r[2]=fmaxf(a[2],b[2]); r[3]=fmaxf(a[3],b[3]); return r;
}
// async global->LDS, 16B/lane; dest = wave-uniform base + lane*16; unsinkable by compiler
__device__ __forceinline__ void gload16(const void* g, void* l){
  __builtin_amdgcn_global_load_lds(
    (const __attribute__((address_space(1))) unsigned int*)g,
    (__attribute__((address_space(3))) unsigned int*)l, 16, 0, 0);
}

// --- K0: Wt transpose (blocks 0-35) + log2-scaled bias table (blocks 36-43) ---
__global__ __launch_bounds__(256) void prep_wt(const float* __restrict__ Wq, const float* __restrict__ Wk,
                        const float* __restrict__ Wv, const float* __restrict__ bias,
                        short* __restrict__ Wt, float* __restrict__ bsc){
  int tid = threadIdx.x;
  if (blockIdx.x >= 36){
    int i = (blockIdx.x - 36)*256 + tid;
    bsc[i] = bias[i] * 1.44269504f;         // log2e — softmax in exp2 domain
    return;
  }
  __shared__ float tile[64][65];
  int mat = blockIdx.x / 12, kblk = blockIdx.x % 12;
  const float* W = (mat == 0) ? Wq : (mat == 1 ? Wk : Wv);
  int k0 = kblk * 64;
  int r = tid >> 2, cq = (tid & 3) * 16;
  #pragma unroll
  for (int i = 0; i < 4; ++i){
    float4 v = *reinterpret_cast<const float4*>(&W[(k0 + r)*H_SZ + cq + i*4]);
    tile[r][cq + i*4 + 0] = v.x; tile[r][cq + i*4 + 1] = v.y;
    tile[r][cq + i*4 + 2] = v.z; tile[r][cq + i*4 + 3] = v.w;
  }
  __syncthreads();
  int n = tid >> 2, kq = (tid & 3) * 16;
  bf16x8 o0, o1;
  #pragma unroll
  for (int e = 0; e < 8; ++e){
    o0[e] = f2bs(tile[kq + e][n]);
    o1[e] = f2bs(tile[kq + 8 + e][n]);
  }
  *reinterpret_cast<bf16x8*>(&Wt[(mat*64 + n)*C_SZ + k0 + kq])     = o0;
  *reinterpret_cast<bf16x8*>(&Wt[(mat*64 + n)*C_SZ + k0 + kq + 8]) = o1;
}

// --- K1: QKV GEMM, A and B async-staged via global_load_lds, double-buffered ---
__global__ __launch_bounds__(512, 2) void qkv_gemm(const float* __restrict__ x, const short* __restrict__ Wt,
                         short* __restrict__ qb, short* __restrict__ kb, short* __restrict__ vT){
  __shared__ float As[2][2048];             // 16 KB: 32 rows x 64 fp32, chunk16-swizzled
  __shared__ short Bs[2][12288];            // 48 KB: 192 rows x 64 bf16, chunk16-swizzled
  int tid = threadIdx.x;
  int wv = tid >> 6, lane = tid & 63, lhi = lane >> 4, llo = lane & 15;
  int wm = wv >> 2, wn = wv & 3;
  long R0 = (long)blockIdx.x * 32;

  int srow = tid >> 4;
  int schunk = (tid & 15) ^ (srow & 7);
  const float* gsrcA = &x[(R0 + srow)*C_SZ + schunk*4];
  float* ldstA = &As[0][wv*256];

  int bn = tid >> 3;
  int bc = (tid & 7) ^ (bn & 7);
  const short* gsrcB0 = &Wt[(  0 + bn)*C_SZ + bc*8];
  const short* gsrcB1 = &Wt[( 64 + bn)*C_SZ + bc*8];
  const short* gsrcB2 = &Wt[(128 + bn)*C_SZ + bc*8];
  short* ldstB = &Bs[0][wv*512];

  f32x4 acc[3];
  #pragma unroll
  for (int j = 0; j < 3; ++j) acc[j] = (f32x4){0.f,0.f,0.f,0.f};

  int rr = wm*16 + llo;
  int r7 = rr & 7, lhi2 = lhi*2;
  int c0 = ((lhi2    ) ^ r7) << 2;
  int c1 = ((lhi2 + 1) ^ r7) << 2;
  int c2 = ((lhi2 + 8) ^ r7) << 2;
  int c3 = ((lhi2 + 9) ^ r7) << 2;
  int nrow[3];
  #pragma unroll
  for (int j = 0; j < 3; ++j) nrow[j] = (wn*48 + j*16 + llo)*64;
  int llo7 = llo & 7;
  int bo0 = ((    lhi) ^ llo7)*8;
  int bo1 = ((4 + lhi) ^ llo7)*8;

#define STAGE(T, BUF) { \
    gload16(gsrcA  + (T)*64, ldstA + (BUF)*2048); \
    gload16(gsrcB0 + (T)*64, ldstB + (BUF)*12288); \
    gload16(gsrcB1 + (T)*64, ldstB + (BUF)*12288 + 4096); \
    gload16(gsrcB2 + (T)*64, ldstB + (BUF)*12288 + 8192); }

  STAGE(0, 0);
  __syncthreads();

  for (int t = 0; t < 12; ++t){
    int cb = t & 1;
    if (t < 11) STAGE(t + 1, cb ^ 1);
    const float* Ar = &As[cb][rr*64];
    f32x4 a0 = *reinterpret_cast<const f32x4*>(Ar + c0);
    f32x4 a1 = *reinterpret_cast<const f32x4*>(Ar + c1);
    f32x4 a2 = *reinterpret_cast<const f32x4*>(Ar + c2);
    f32x4 a3 = *reinterpret_cast<const f32x4*>(Ar + c3);
    bf16x8 af0, af1;
    #pragma unroll
    for (int e = 0; e < 4; ++e){
      af0[e]   = f2bs(a0[e]); af0[4+e] = f2bs(a1[e]);
      af1[e]   = f2bs(a2[e]); af1[4+e] = f2bs(a3[e]);
    }
    const short* Br = &Bs[cb][0];
    #pragma unroll
    for (int j = 0; j < 3; ++j){
      bf16x8 b0 = *reinterpret_cast<const bf16x8*>(Br + nrow[j] + bo0);
      bf16x8 b1 = *reinterpret_cast<const bf16x8*>(Br + nrow[j] + bo1);
      acc[j] = __builtin_amdgcn_mfma_f32_16x16x32_bf16(af0, b0, acc[j], 0, 0, 0);
      acc[j] = __builtin_amdgcn_mfma_f32_16x16x32_bf16(af1, b1, acc[j], 0, 0, 0);
    }
    __syncthreads();
  }
#undef STAGE

  long mbase = R0 + wm*16 + lhi*4;
  #pragma unroll
  for (int j = 0; j < 3; ++j){
    int n = wn*48 + j*16 + llo;
    int mat = n >> 6, c = n & 63;
    if (mat == 2){
      long b = mbase >> 11, t = mbase & 2047;
      short4v p;
      #pragma unroll
      for (int reg = 0; reg < 4; ++reg) p[reg] = f2bs(acc[j][reg]);
      *reinterpret_cast<short4v*>(&vT[(b*H_SZ + c)*T_SZ + t]) = p;
    } else {
      short* dst = (mat == 0) ? qb : kb;
      #pragma unroll
      for (int reg = 0; reg < 4; ++reg)
        dst[(mbase + reg)*H_SZ + c] = f2bs(acc[j][reg]);
    }
  }
}

// --- K2: flash attention v2 — shared-KV dual q-tile, 8-way kv split, shfl-free softmax
//     (byte-exact restore of the verified 42.9us / absmax 0.0156 kernel) ---
__global__ __launch_bounds__(512, 4) void attn_fwd(const short* __restrict__ qb, const short* __restrict__ kb,
                        const short* __restrict__ vT, const float* __restrict__ bsc,
                        float* __restrict__ out){
  __shared__ float bias_s[2048];            // 8 KB
  __shared__ short P_lds[8][2][1152];       // 36.9 KB; aliased as o_part during merge
  __shared__ float m_part[8][16];
  __shared__ float l_part[8][4][16];        // per-lhi l partials (shfl-free l)
  float* OP = (float*)&P_lds[0][0][0];      // merge view: [w][row][d] @ w*1152 + row*65 + d

  int tid = threadIdx.x;
  for (int i = tid; i < 2048; i += 512) bias_s[i] = bsc[i];

  int wv = tid >> 6, lane = tid & 63, lhi = lane >> 4, llo = lane & 15;
  int b = blockIdx.x & 7, jj = blockIdx.x >> 3;   // batch -> XCD affinity
  int qtA = jj, qtB = 127 - jj;             // qtA subset range of qtB
  int qA = qtA*16 + llo, qB = qtB*16 + llo;
  int nktA = (qtA >> 2) + 1, nktB = (qtB >> 2) + 1;

  const short* qrA = &qb[((long)(b*T_SZ + qA))*H_SZ + lhi*8];
  const short* qrB = &qb[((long)(b*T_SZ + qB))*H_SZ + lhi*8];
  bf16x8 qfA0 = *reinterpret_cast<const bf16x8*>(qrA);
  bf16x8 qfA1 = *reinterpret_cast<const bf16x8*>(qrA + 32);
  bf16x8 qfB0 = *reinterpret_cast<const bf16x8*>(qrB);
  bf16x8 qfB1 = *reinterpret_cast<const bf16x8*>(qrB + 32);
  const short* kbase = kb + (long)b*T_SZ*H_SZ;
  const short* vbase = vT + (long)b*H_SZ*T_SZ;
  __syncthreads();

  float mA = -1e30f, lA = 0.f, mB = -1e30f, lB = 0.f;
  f32x4 oA[4], oB[4];
  #pragma unroll
  for (int df = 0; df < 4; ++df){ oA[df] = (f32x4){0.f,0.f,0.f,0.f}; oB[df] = (f32x4){0.f,0.f,0.f,0.f}; }

  // softmax (shfl-free common path) + P write + P-frag read
#define SM(S, M, L, O, QV, TI, PB0, PB1) {                                  \
    _Pragma("unroll") for (int f = 0; f < 4; ++f)                           \
      _Pragma("unroll") for (int rg = 0; rg < 4; ++rg){                     \
        int kv = kv0 + f*16 + lhi*4 + rg;                                   \
        int rel = (QV) - kv;                                                \
        float bv = bias_s[rel > 0 ? rel : 0];                               \
        S[f][rg] = (rel >= 0) ? fmaf(S[f][rg], 0.18033688f, bv) : -1e30f; } \
    f32x4 tm = vmax4(vmax4(S[0], S[1]), vmax4(S[2], S[3]));                 \
    float pmax = fmaxf(fmaxf(tm[0], tm[1]), fmaxf(tm[2], tm[3]));           \
    if (!__all(pmax <= M + 8.0f)){                                          \
      float rm = fmaxf(pmax, __shfl_xor(pmax, 16));                         \
      rm = fmaxf(rm, __shfl_xor(rm, 32));                                   \
      float mnew = fmaxf(M, rm);                                            \
      float corr = exp2f(M - mnew);                                         \
      M = mnew; L *= corr;                                                  \
      _Pragma("unroll") for (int df = 0; df < 4; ++df) O[df] = O[df]*corr; }\
    _Pragma("unroll") for (int f = 0; f < 4; ++f){                          \
      short4v pk;                                                           \
      _Pragma("unroll") for (int rg = 0; rg < 4; ++rg){                     \
        float p = exp2f(S[f][rg] - M); S[f][rg] = p; pk[rg] = f2bs(p); }    \
      *reinterpret_cast<short4v*>(&P_lds[wv][TI][llo*72 + f*16 + lhi*4]) = pk; } \
    f32x4 va = (S[0] + S[1]) + (S[2] + S[3]);                               \
    L += (va[0] + va[1]) + (va[2] + va[3]);                                 \
    PB0 = *reinterpret_cast<const bf16x8*>(&P_lds[wv][TI][llo*72 + lhi*8]); \
    PB1 = *reinterpret_cast<const bf16x8*>(&P_lds[wv][TI][llo*72 + 32 + lhi*8]); }

  for (int c = wv; c < nktB; c += 8){       // each kv-tile loaded ONCE, used by both q-tiles
    int kv0 = c * 64;
    bool doA = c < nktA;
    f32x4 sA[4], sB[4];
    #pragma unroll
    for (int f = 0; f < 4; ++f){
      const short* kr = kbase + (long)(kv0 + f*16 + llo)*H_SZ + lhi*8;
      bf16x8 k0 = *reinterpret_cast<const bf16x8*>(kr);
      bf16x8 k1 = *reinterpret_cast<const bf16x8*>(kr + 32);
      f32x4 t = (f32x4){0.f,0.f,0.f,0.f};
      t = __builtin_amdgcn_mfma_f32_16x16x32_bf16(k0, qfB0, t, 0, 0, 0);
      t = __builtin_amdgcn_mfma_f32_16x16x32_bf16(k1, qfB1, t, 0, 0, 0);
      sB[f] = t;
      f32x4 u = (f32x4){0.f,0.f,0.f,0.f};   // independent second chain (ILP)
      u = __builtin_amdgcn_mfma_f32_16x16x32_bf16(k0, qfA0, u, 0, 0, 0);
      u = __builtin_amdgcn_mfma_f32_16x16x32_bf16(k1, qfA1, u, 0, 0, 0);
      sA[f] = u;
    }
    bf16x8 pbB0, pbB1;
    SM(sB, mB, lB, oB, qB, 1, pbB0, pbB1);
    if (doA){
      bf16x8 pbA0, pbA1;
      SM(sA, mA, lA, oA, qA, 0, pbA0, pbA1);
      #pragma unroll
      for (int df = 0; df < 4; ++df){
        const short* vr = vbase + (long)(df*16 + llo)*T_SZ + kv0 + lhi*8;
        bf16x8 v0 = *reinterpret_cast<const bf16x8*>(vr);
        bf16x8 v1 = *reinterpret_cast<const bf16x8*>(vr + 32);
        oB[df] = __builtin_amdgcn_mfma_f32_16x16x32_bf16(v0, pbB0, oB[df], 0, 0, 0);
        oB[df] = __builtin_amdgcn_mfma_f32_16x16x32_bf16(v1, pbB1, oB[df], 0, 0, 0);
        oA[df] = __builtin_amdgcn_mfma_f32_16x16x32_bf16(v0, pbA0, oA[df], 0, 0, 0);
        oA[df] = __builtin_amdgcn_mfma_f32_16x16x32_bf16(v1, pbA1, oA[df], 0, 0, 0);
      }
    } else {
      #pragma unroll
      for (int df = 0; df < 4; ++df){
        const short* vr = vbase + (long)(df*16 + llo)*T_SZ + kv0 + lhi*8;
        bf16x8 v0 = *reinterpret_cast<const bf16x8*>(vr);
        bf16x8 v1 = *reinterpret_cast<const bf16x8*>(vr + 32);
        oB[df] = __builtin_amdgcn_mfma_f32_16x16x32_bf16(v0, pbB0, oB[df], 0, 0, 0);
        oB[df] = __builtin_amdgcn_mfma_f32_16x16x32_bf16(v1, pbB1, oB[df], 0, 0, 0);
      }
    }
  }
#undef SM

  // two-phase merge (B then A), o_part aliases P_lds region
#define MERGE(O, M, L, QT) {                                                \
    _Pragma("unroll") for (int df = 0; df < 4; ++df)                        \
      _Pragma("unroll") for (int rg = 0; rg < 4; ++rg)                      \
        OP[wv*1152 + llo*65 + df*16 + lhi*4 + rg] = O[df][rg];              \
    l_part[wv][lhi][llo] = L;                                               \
    if (lhi == 0) m_part[wv][llo] = M;                                      \
    __syncthreads();                                                        \
    { int idx = tid;                                                        \
      _Pragma("unroll") for (int rep = 0; rep < 2; ++rep){                  \
        int row = idx >> 6, d = idx & 63;                                   \
        float mstar = m_part[0][row];                                       \
        _Pragma("unroll") for (int w = 1; w < 8; ++w)                       \
          mstar = fmaxf(mstar, m_part[w][row]);                             \
        float lsum = 0.f, osum = 0.f;                                       \
        _Pragma("unroll") for (int w = 0; w < 8; ++w){                      \
          float sc = exp2f(m_part[w][row] - mstar);                         \
          lsum += sc * (l_part[w][0][row] + l_part[w][1][row]               \
                      + l_part[w][2][row] + l_part[w][3][row]);             \
          osum += sc * OP[w*1152 + row*65 + d]; }                           \
        out[((long)(b*T_SZ + (QT)*16 + row))*H_SZ + d] = osum / lsum;       \
        idx += 512; } }                                                     \
    __syncthreads(); }

  MERGE(oB, mB, lB, qtB);
  MERGE(oA, mA, lA, qtA);
#undef MERGE
}

extern "C" void kernel_launch(void* const* d_in, const int* in_sizes, int n_in,
                              void* d_out, int out_size, void* d_ws, size_t ws_size,
                              hipStream_t stream){
  const float* x    = (const float*)d_in[0];
  const float* Wq   = (const float*)d_in[1];
  const float* Wk   = (const float*)d_in[2];
  const float* Wv   = (const float*)d_in[3];
  const float* bias = (const float*)d_in[4];
  float* out = (float*)d_out;

  const size_t NTOK = (size_t)B_SZ * T_SZ * H_SZ;   // 1,048,576
  short* qb = (short*)d_ws;
  short* kb = qb + NTOK;
  short* vT = kb + NTOK;
  short* Wt = vT + NTOK;                            // 192*768 shorts
  float* bsc = (float*)(Wt + 192*C_SZ);             // 2048 floats

  prep_wt<<<44, 256, 0, stream>>>(Wq, Wk, Wv, bias, Wt, bsc);
  qkv_gemm<<<512, 512, 0, stream>>>(x, Wt, qb, kb, vT);
  attn_fwd<<<512, 512, 0, stream>>>(qb, kb, vT, bsc, out);
}